// Round 1
// baseline (322.709 us; speedup 1.0000x reference)
//
#include <hip/hip_runtime.h>
#include <hip/hip_bf16.h>

// Problem constants (SparseMultiheadAttention_429496729817):
// B=2, N=10000, M=320000, QD=KD=HD=256, NUM_HEADS=8, dh=32.
#define DHID 256
#define NHEAD 8
#define BATCH 2

// ---------------- GEMM: C(Mrows x 256) = A(Mrows x 256) @ W(256 x 256) ----
// Classic 64x64 tile, BK=16, 256 threads, 4x4 micro-tile per thread. fp32.
#define TILE 64
#define BK 16

__global__ __launch_bounds__(256) void gemm_kernel(
    const float* __restrict__ Xq, const float* __restrict__ Xk,
    const float* __restrict__ Wq, const float* __restrict__ Wk,
    float* __restrict__ Qo, float* __restrict__ Ko, int Mrows)
{
    const float* A = (blockIdx.z == 0) ? Xq : Xk;
    const float* W = (blockIdx.z == 0) ? Wq : Wk;
    float* C       = (blockIdx.z == 0) ? Qo : Ko;

    __shared__ float As[TILE][BK + 1];   // +1 pad: column reads conflict-free
    __shared__ float Ws[BK][TILE];

    const int t  = threadIdx.x;
    const int ty = t >> 4;         // 0..15
    const int tx = t & 15;         // 0..15
    const int rowBase = blockIdx.x * TILE;
    const int colBase = blockIdx.y * TILE;

    // staging load indices
    const int la_row = t >> 2;          // 0..63
    const int la_col = (t & 3) * 4;     // 0,4,8,12
    const int lw_row = t >> 4;          // 0..15
    const int lw_col = (t & 15) * 4;    // 0..60

    float acc[4][4] = {};

    for (int k0 = 0; k0 < DHID; k0 += BK) {
        // A tile (64x16)
        int ar = rowBase + la_row;
        float4 av = make_float4(0.f, 0.f, 0.f, 0.f);
        if (ar < Mrows) av = *(const float4*)(A + (size_t)ar * DHID + k0 + la_col);
        As[la_row][la_col + 0] = av.x;
        As[la_row][la_col + 1] = av.y;
        As[la_row][la_col + 2] = av.z;
        As[la_row][la_col + 3] = av.w;
        // W tile (16x64)
        float4 wv = *(const float4*)(W + (size_t)(k0 + lw_row) * DHID + colBase + lw_col);
        *(float4*)&Ws[lw_row][lw_col] = wv;
        __syncthreads();

#pragma unroll
        for (int kk = 0; kk < BK; ++kk) {
            float a0 = As[ty * 4 + 0][kk];
            float a1 = As[ty * 4 + 1][kk];
            float a2 = As[ty * 4 + 2][kk];
            float a3 = As[ty * 4 + 3][kk];
            float4 w = *(const float4*)&Ws[kk][tx * 4];
            acc[0][0] += a0 * w.x; acc[0][1] += a0 * w.y; acc[0][2] += a0 * w.z; acc[0][3] += a0 * w.w;
            acc[1][0] += a1 * w.x; acc[1][1] += a1 * w.y; acc[1][2] += a1 * w.z; acc[1][3] += a1 * w.w;
            acc[2][0] += a2 * w.x; acc[2][1] += a2 * w.y; acc[2][2] += a2 * w.z; acc[2][3] += a2 * w.w;
            acc[3][0] += a3 * w.x; acc[3][1] += a3 * w.y; acc[3][2] += a3 * w.z; acc[3][3] += a3 * w.w;
        }
        __syncthreads();
    }

#pragma unroll
    for (int i = 0; i < 4; ++i) {
        int row = rowBase + ty * 4 + i;
        if (row < Mrows) {
            float4 v = make_float4(acc[i][0], acc[i][1], acc[i][2], acc[i][3]);
            *(float4*)(C + (size_t)row * DHID + colBase + tx * 4) = v;
        }
    }
}

// ---------------- Edge kernel: one wave per edge --------------------------
// a[b,e,h] = sum_{j in head h} q[b,src,j]*k[b,dst,j] / 16 ; e = exp(a)
// (global max subtraction cancels in e/seg -> skipped)
__global__ __launch_bounds__(256) void edge_kernel(
    const float* __restrict__ Q, const float* __restrict__ K,
    const int* __restrict__ mask, float* __restrict__ out,
    float* __restrict__ seg, int M, int N)
{
    const int wave = threadIdx.x >> 6;
    const int lane = threadIdx.x & 63;
    const int e = blockIdx.x * 4 + wave;
    const int b = blockIdx.y;
    if (e >= M) return;

    const int src = mask[e];
    const int dst = mask[M + e];

    const float4* qrow = (const float4*)(Q + ((size_t)b * N + src) * DHID);
    const float4* krow = (const float4*)(K + ((size_t)b * N + dst) * DHID);
    float4 qv = qrow[lane];
    float4 kv = krow[lane];
    float s = qv.x * kv.x + qv.y * kv.y + qv.z * kv.z + qv.w * kv.w;
    // reduce within 8-lane head groups (lanes 8h..8h+7 = head h)
    s += __shfl_xor(s, 1);
    s += __shfl_xor(s, 2);
    s += __shfl_xor(s, 4);
    // lane l (<8) fetches head l's sum from lane 8l
    float v = __shfl(s, (lane << 3) & 63);
    if (lane < NHEAD) {
        float ev = expf(v * 0.0625f);   // 1/sqrt(256) = 1/16
        out[((size_t)b * M + e) * NHEAD + lane] = ev;
        atomicAdd(seg + ((size_t)b * N + src) * NHEAD + lane, ev);
    }
}

// ---------------- Normalize: out = e / (seg[src] + 1e-16) -----------------
__global__ __launch_bounds__(256) void norm_kernel(
    const int* __restrict__ mask, const float* __restrict__ seg,
    float* __restrict__ out, int M, int N, int BM)
{
    int idx = blockIdx.x * 256 + threadIdx.x;   // idx = b*M + e
    if (idx >= BM) return;
    int b = idx / M;
    int e = idx - b * M;
    int src = mask[e];
    const float4* s4 = (const float4*)(seg + ((size_t)b * N + src) * NHEAD);
    float4 s0 = s4[0], s1 = s4[1];
    float4* o4 = (float4*)(out + (size_t)idx * NHEAD);
    float4 o0 = o4[0], o1 = o4[1];
    o0.x /= (s0.x + 1e-16f); o0.y /= (s0.y + 1e-16f);
    o0.z /= (s0.z + 1e-16f); o0.w /= (s0.w + 1e-16f);
    o1.x /= (s1.x + 1e-16f); o1.y /= (s1.y + 1e-16f);
    o1.z /= (s1.z + 1e-16f); o1.w /= (s1.w + 1e-16f);
    o4[0] = o0; o4[1] = o1;
}

extern "C" void kernel_launch(void* const* d_in, const int* in_sizes, int n_in,
                              void* d_out, int out_size, void* d_ws, size_t ws_size,
                              hipStream_t stream) {
    const float* x_q  = (const float*)d_in[0];
    const float* x_k  = (const float*)d_in[1];
    const int*   mask = (const int*)d_in[2];
    const float* w_q  = (const float*)d_in[3];
    const float* w_k  = (const float*)d_in[4];
    float* out = (float*)d_out;

    const int M = in_sizes[2] / 2;                 // 320000
    const int N = in_sizes[0] / (BATCH * DHID);    // 10000
    const int Mrows = BATCH * N;                   // 20000

    float* Q   = (float*)d_ws;
    float* K   = Q + (size_t)Mrows * DHID;
    float* seg = K + (size_t)Mrows * DHID;

    hipMemsetAsync(seg, 0, (size_t)BATCH * N * NHEAD * sizeof(float), stream);

    dim3 ggrid((Mrows + TILE - 1) / TILE, DHID / TILE, 2);
    gemm_kernel<<<ggrid, 256, 0, stream>>>(x_q, x_k, w_q, w_k, Q, K, Mrows);

    dim3 egrid((M + 3) / 4, BATCH);
    edge_kernel<<<egrid, 256, 0, stream>>>(Q, K, mask, out, seg, M, N);

    const int BM = BATCH * M;
    norm_kernel<<<(BM + 255) / 256, 256, 0, stream>>>(mask, seg, out, M, N, BM);
}

// Round 2
// 241.708 us; speedup vs baseline: 1.3351x; 1.3351x over previous
//
#include <hip/hip_runtime.h>
#include <hip/hip_bf16.h>
#include <hip/hip_fp16.h>

// Problem constants: B=2, N=10000, M=320000, QD=KD=HD=256, NUM_HEADS=8, dh=32.
#define DHID 256
#define NHEAD 8
#define BATCH 2

typedef _Float16 h8 __attribute__((ext_vector_type(8)));
typedef _Float16 h4 __attribute__((ext_vector_type(4)));
typedef float f4 __attribute__((ext_vector_type(4)));

// ---------------- W transpose + fp16 convert: Wt[n][k] = (half)W[k][n] -----
__global__ __launch_bounds__(256) void transpose_w(
    const float* __restrict__ Wq, const float* __restrict__ Wk,
    _Float16* __restrict__ Wtq, _Float16* __restrict__ Wtk)
{
    const float* W = blockIdx.z ? Wk : Wq;
    _Float16* Wt   = blockIdx.z ? Wtk : Wtq;
    __shared__ float tile[32][33];
    const int tx = threadIdx.x;   // 0..31
    const int ty = threadIdx.y;   // 0..7
    const int n0 = blockIdx.x * 32;
    const int k0 = blockIdx.y * 32;
#pragma unroll
    for (int j = 0; j < 32; j += 8)
        tile[ty + j][tx] = W[(size_t)(k0 + ty + j) * DHID + n0 + tx];
    __syncthreads();
#pragma unroll
    for (int j = 0; j < 32; j += 8)
        Wt[(size_t)(n0 + ty + j) * DHID + k0 + tx] = (_Float16)tile[tx][ty + j];
}

// ---------------- MFMA GEMM: C(Mrows x 256) = X(Mrows x 256) @ W ----------
// 64x64 tile per 256-thread block; full K=256 staged once in 64 KB LDS.
// XOR swizzle on 16B chunks breaks the row-stride-512B bank pattern
// (plain layout -> all 16 frag-rows hit the same bank group, 16-way).
__global__ __launch_bounds__(256, 2) void gemm_mfma(
    const float* __restrict__ Xq, const float* __restrict__ Xk,
    const _Float16* __restrict__ Wtq, const _Float16* __restrict__ Wtk,
    _Float16* __restrict__ Qh, _Float16* __restrict__ Kh, int Mrows)
{
    const float* X       = blockIdx.z ? Xk : Xq;
    const _Float16* Wt   = blockIdx.z ? Wtk : Wtq;
    _Float16* C          = blockIdx.z ? Kh : Qh;

    __shared__ _Float16 As[64 * 256];   // 32 KB, [row][k] swizzled
    __shared__ _Float16 Bs[64 * 256];   // 32 KB, [n][k]   swizzled

    const int t    = threadIdx.x;
    const int lane = t & 63;
    const int wave = t >> 6;
    const int rowBase = blockIdx.x * 64;
    const int colBase = blockIdx.y * 64;

    // stage A: 64 rows x 256 k, fp32 -> fp16. chunk = 8 halves = 16B, 32/row.
#pragma unroll
    for (int i = 0; i < 8; ++i) {
        int idx = t + i * 256;          // 0..2047
        int row = idx >> 5;
        int c   = idx & 31;
        int grow = rowBase + row;
        f4 v0 = {0,0,0,0}, v1 = {0,0,0,0};
        if (grow < Mrows) {
            const float* p = X + (size_t)grow * DHID + c * 8;
            v0 = *(const f4*)p;
            v1 = *(const f4*)(p + 4);
        }
        h8 hv;
        hv[0]=(_Float16)v0[0]; hv[1]=(_Float16)v0[1]; hv[2]=(_Float16)v0[2]; hv[3]=(_Float16)v0[3];
        hv[4]=(_Float16)v1[0]; hv[5]=(_Float16)v1[1]; hv[6]=(_Float16)v1[2]; hv[7]=(_Float16)v1[3];
        int sc = c ^ (row & 7);
        *(h8*)&As[row * 256 + sc * 8] = hv;
    }
    // stage B: 64 n-rows x 256 k from fp16 Wt (contiguous 16B loads).
#pragma unroll
    for (int i = 0; i < 8; ++i) {
        int idx = t + i * 256;
        int n = idx >> 5;
        int c = idx & 31;
        h8 hv = *(const h8*)(Wt + (size_t)(colBase + n) * DHID + c * 8);
        int sc = c ^ (n & 7);
        *(h8*)&Bs[n * 256 + sc * 8] = hv;
    }
    __syncthreads();

    // wave handles rows [wave*16, wave*16+16) x 4 col-tiles of 16.
    // A frag: A[m=lane&15][k=quad*8+j]; B frag: B[n=lane&15][k=quad*8+j].
    const int ar   = wave * 16 + (lane & 15);
    const int quad = lane >> 4;
    f4 acc[4] = {{0,0,0,0},{0,0,0,0},{0,0,0,0},{0,0,0,0}};
#pragma unroll
    for (int kc = 0; kc < 8; ++kc) {            // K chunk of 32
        int ac = (kc * 4 + quad) ^ (ar & 7);
        h8 afrag = *(const h8*)&As[ar * 256 + ac * 8];
#pragma unroll
        for (int ct = 0; ct < 4; ++ct) {
            int bn = ct * 16 + (lane & 15);
            int bc = (kc * 4 + quad) ^ (bn & 7);
            h8 bfrag = *(const h8*)&Bs[bn * 256 + bc * 8];
            acc[ct] = __builtin_amdgcn_mfma_f32_16x16x32_f16(afrag, bfrag, acc[ct], 0, 0, 0);
        }
    }

    // epilogue: D[row=quad*4+r][col=lane&15]; fp16-only output.
#pragma unroll
    for (int ct = 0; ct < 4; ++ct) {
#pragma unroll
        for (int r = 0; r < 4; ++r) {
            int grow = rowBase + wave * 16 + quad * 4 + r;
            if (grow < Mrows)
                C[(size_t)grow * DHID + colBase + ct * 16 + (lane & 15)] = (_Float16)acc[ct][r];
        }
    }
}

// ---------------- Edge kernel: one wave per (edge, batch), fp16 rows ------
// Global max subtraction cancels in e/seg -> skipped.
__global__ __launch_bounds__(256) void edge_kernel(
    const _Float16* __restrict__ Qh, const _Float16* __restrict__ Kh,
    const int* __restrict__ mask, float* __restrict__ out,
    float* __restrict__ seg, int M, int N)
{
    const int wave = threadIdx.x >> 6;
    const int lane = threadIdx.x & 63;
    const int e = blockIdx.x * 4 + wave;
    const int b = blockIdx.y;
    if (e >= M) return;

    const int src = mask[e];
    const int dst = mask[M + e];

    const h4* qrow = (const h4*)(Qh + ((size_t)b * N + src) * DHID);
    const h4* krow = (const h4*)(Kh + ((size_t)b * N + dst) * DHID);
    h4 qv = qrow[lane];   // lane owns channels [4*lane, 4*lane+4)
    h4 kv = krow[lane];
    float s = (float)qv[0] * (float)kv[0] + (float)qv[1] * (float)kv[1]
            + (float)qv[2] * (float)kv[2] + (float)qv[3] * (float)kv[3];
    // head h = lanes [8h, 8h+8): butterfly within 8-lane groups
    s += __shfl_xor(s, 1);
    s += __shfl_xor(s, 2);
    s += __shfl_xor(s, 4);
    float v = __shfl(s, (lane << 3) & 63);
    if (lane < NHEAD) {
        float ev = expf(v * 0.0625f);   // 1/sqrt(256) = 1/16
        out[((size_t)b * M + e) * NHEAD + lane] = ev;
        atomicAdd(seg + ((size_t)b * N + src) * NHEAD + lane, ev);
    }
}

// ---------------- Normalize: out = e / (seg[src] + 1e-16) -----------------
__global__ __launch_bounds__(256) void norm_kernel(
    const int* __restrict__ mask, const float* __restrict__ seg,
    float* __restrict__ out, int M, int N, int BM)
{
    int idx = blockIdx.x * 256 + threadIdx.x;   // idx = b*M + e
    if (idx >= BM) return;
    int b = idx / M;
    int e = idx - b * M;
    int src = mask[e];
    const float4* s4 = (const float4*)(seg + ((size_t)b * N + src) * NHEAD);
    float4 s0 = s4[0], s1 = s4[1];
    float4* o4 = (float4*)(out + (size_t)idx * NHEAD);
    float4 o0 = o4[0], o1 = o4[1];
    o0.x /= (s0.x + 1e-16f); o0.y /= (s0.y + 1e-16f);
    o0.z /= (s0.z + 1e-16f); o0.w /= (s0.w + 1e-16f);
    o1.x /= (s1.x + 1e-16f); o1.y /= (s1.y + 1e-16f);
    o1.z /= (s1.z + 1e-16f); o1.w /= (s1.w + 1e-16f);
    o4[0] = o0; o4[1] = o1;
}

extern "C" void kernel_launch(void* const* d_in, const int* in_sizes, int n_in,
                              void* d_out, int out_size, void* d_ws, size_t ws_size,
                              hipStream_t stream) {
    const float* x_q  = (const float*)d_in[0];
    const float* x_k  = (const float*)d_in[1];
    const int*   mask = (const int*)d_in[2];
    const float* w_q  = (const float*)d_in[3];
    const float* w_k  = (const float*)d_in[4];
    float* out = (float*)d_out;

    const int M = in_sizes[2] / 2;                 // 320000
    const int N = in_sizes[0] / (BATCH * DHID);    // 10000
    const int Mrows = BATCH * N;                   // 20000

    _Float16* Qh  = (_Float16*)d_ws;
    _Float16* Kh  = Qh  + (size_t)Mrows * DHID;
    _Float16* Wtq = Kh  + (size_t)Mrows * DHID;
    _Float16* Wtk = Wtq + (size_t)DHID * DHID;
    float*    seg = (float*)(Wtk + (size_t)DHID * DHID);

    hipMemsetAsync(seg, 0, (size_t)BATCH * N * NHEAD * sizeof(float), stream);

    dim3 tgrid(DHID / 32, DHID / 32, 2);
    transpose_w<<<tgrid, dim3(32, 8), 0, stream>>>(w_q, w_k, Wtq, Wtk);

    dim3 ggrid((Mrows + 63) / 64, DHID / 64, 2);
    gemm_mfma<<<ggrid, 256, 0, stream>>>(x_q, x_k, Wtq, Wtk, Qh, Kh, Mrows);

    dim3 egrid((M + 3) / 4, BATCH);
    edge_kernel<<<egrid, 256, 0, stream>>>(Qh, Kh, mask, out, seg, M, N);

    const int BM = BATCH * M;
    norm_kernel<<<(BM + 255) / 256, 256, 0, stream>>>(mask, seg, out, M, N, BM);
}

// Round 3
// 185.195 us; speedup vs baseline: 1.7425x; 1.3052x over previous
//
#include <hip/hip_runtime.h>
#include <hip/hip_bf16.h>
#include <hip/hip_fp16.h>

// Problem constants: B=2, N=10000, M=320000, QD=KD=HD=256, NUM_HEADS=8, dh=32.
#define DHID 256
#define NHEAD 8
#define BATCH 2

typedef _Float16 h8 __attribute__((ext_vector_type(8)));
typedef float f4 __attribute__((ext_vector_type(4)));

// ---------------- W transpose + fp16 convert: Wt[n][k] = (half)W[k][n] -----
__global__ __launch_bounds__(256) void transpose_w(
    const float* __restrict__ Wq, const float* __restrict__ Wk,
    _Float16* __restrict__ Wtq, _Float16* __restrict__ Wtk)
{
    const float* W = blockIdx.z ? Wk : Wq;
    _Float16* Wt   = blockIdx.z ? Wtk : Wtq;
    __shared__ float tile[32][33];
    const int tx = threadIdx.x;   // 0..31
    const int ty = threadIdx.y;   // 0..7
    const int n0 = blockIdx.x * 32;
    const int k0 = blockIdx.y * 32;
#pragma unroll
    for (int j = 0; j < 32; j += 8)
        tile[ty + j][tx] = W[(size_t)(k0 + ty + j) * DHID + n0 + tx];
    __syncthreads();
#pragma unroll
    for (int j = 0; j < 32; j += 8)
        Wt[(size_t)(n0 + ty + j) * DHID + k0 + tx] = (_Float16)tile[tx][ty + j];
}

// ---------------- MFMA GEMM, A-stationary --------------------------------
// grid (Mrows/64, 1, 2). Block stages its 64x256 A-tile ONCE (32 KB),
// then loops the 4 column tiles restaging only B (W^T, 128 KB, L2-hot).
// X is read exactly once (41 MB total vs 164 MB in round 2).
__global__ __launch_bounds__(256, 2) void gemm_mfma(
    const float* __restrict__ Xq, const float* __restrict__ Xk,
    const _Float16* __restrict__ Wtq, const _Float16* __restrict__ Wtk,
    _Float16* __restrict__ Qh, _Float16* __restrict__ Kh, int Mrows)
{
    const float* X       = blockIdx.z ? Xk : Xq;
    const _Float16* Wt   = blockIdx.z ? Wtk : Wtq;
    _Float16* C          = blockIdx.z ? Kh : Qh;

    __shared__ _Float16 As[64 * 256];   // 32 KB, [row][k] swizzled
    __shared__ _Float16 Bs[64 * 256];   // 32 KB, [n][k]   swizzled

    const int t    = threadIdx.x;
    const int lane = t & 63;
    const int wave = t >> 6;
    const int rowBase = blockIdx.x * 64;

    // stage A: 64 rows x 256 k, fp32 -> fp16. chunk = 8 halves = 16B, 32/row.
#pragma unroll
    for (int i = 0; i < 8; ++i) {
        int idx = t + i * 256;          // 0..2047
        int row = idx >> 5;
        int c   = idx & 31;
        int grow = rowBase + row;
        f4 v0 = {0,0,0,0}, v1 = {0,0,0,0};
        if (grow < Mrows) {
            const float* p = X + (size_t)grow * DHID + c * 8;
            v0 = *(const f4*)p;
            v1 = *(const f4*)(p + 4);
        }
        h8 hv;
        hv[0]=(_Float16)v0[0]; hv[1]=(_Float16)v0[1]; hv[2]=(_Float16)v0[2]; hv[3]=(_Float16)v0[3];
        hv[4]=(_Float16)v1[0]; hv[5]=(_Float16)v1[1]; hv[6]=(_Float16)v1[2]; hv[7]=(_Float16)v1[3];
        int sc = c ^ (row & 7);
        *(h8*)&As[row * 256 + sc * 8] = hv;
    }

    const int ar   = wave * 16 + (lane & 15);
    const int quad = lane >> 4;

    for (int ct64 = 0; ct64 < 4; ++ct64) {
        // stage B: 64 n-rows x 256 k from fp16 Wt (contiguous 16B loads).
#pragma unroll
        for (int i = 0; i < 8; ++i) {
            int idx = t + i * 256;
            int n = idx >> 5;
            int c = idx & 31;
            h8 hv = *(const h8*)(Wt + (size_t)(ct64 * 64 + n) * DHID + c * 8);
            int sc = c ^ (n & 7);
            *(h8*)&Bs[n * 256 + sc * 8] = hv;
        }
        __syncthreads();

        f4 acc[4] = {{0,0,0,0},{0,0,0,0},{0,0,0,0},{0,0,0,0}};
#pragma unroll
        for (int kc = 0; kc < 8; ++kc) {            // K chunk of 32
            int ac = (kc * 4 + quad) ^ (ar & 7);
            h8 afrag = *(const h8*)&As[ar * 256 + ac * 8];
#pragma unroll
            for (int ct = 0; ct < 4; ++ct) {
                int bn = ct * 16 + (lane & 15);
                int bc = (kc * 4 + quad) ^ (bn & 7);
                h8 bfrag = *(const h8*)&Bs[bn * 256 + bc * 8];
                acc[ct] = __builtin_amdgcn_mfma_f32_16x16x32_f16(afrag, bfrag, acc[ct], 0, 0, 0);
            }
        }

        // epilogue: D[row=quad*4+r][col=lane&15]
#pragma unroll
        for (int ct = 0; ct < 4; ++ct) {
#pragma unroll
            for (int r = 0; r < 4; ++r) {
                int grow = rowBase + wave * 16 + quad * 4 + r;
                if (grow < Mrows)
                    C[(size_t)grow * DHID + ct64 * 64 + ct * 16 + (lane & 15)] = (_Float16)acc[ct][r];
            }
        }
        __syncthreads();
    }
}

// ---------------- Edge kernel: 8 edges/wave, lane = (edge g, head h) ------
// lane 8g+h owns head h (32 contiguous channels) of edge g: in-lane dot,
// no shuffles for the reduction, exp/store/atomic on all 64 lanes.
// Global max subtraction cancels in e/seg -> skipped.
__global__ __launch_bounds__(256) void edge_kernel(
    const _Float16* __restrict__ Qh, const _Float16* __restrict__ Kh,
    const int* __restrict__ mask, float* __restrict__ out,
    float* __restrict__ seg, int M, int N)
{
    const int lane = threadIdx.x & 63;
    const int wave = threadIdx.x >> 6;
    const int g = lane >> 3;        // edge-in-wave 0..7
    const int h = lane & 7;         // head 0..7
    const long e0 = ((long)blockIdx.x * 4 + wave) * 8;
    const int b = blockIdx.y;
    if (e0 >= M) return;

    // lanes 0..7 load the 8 src indices, lanes 8..15 the 8 dst indices
    int idxv = 0;
    {
        long le = e0 + (lane & 7);
        if (le >= M) le = M - 1;
        if (lane < 8)       idxv = mask[le];
        else if (lane < 16) idxv = mask[M + le];
    }
    const int src = __shfl(idxv, g);
    const int dst = __shfl(idxv, 8 + g);

    const _Float16* qp = Qh + ((size_t)b * N + src) * DHID + h * 32;
    const _Float16* kp = Kh + ((size_t)b * N + dst) * DHID + h * 32;
    float s = 0.f;
#pragma unroll
    for (int j = 0; j < 4; ++j) {
        h8 qv = *(const h8*)(qp + j * 8);
        h8 kv = *(const h8*)(kp + j * 8);
#pragma unroll
        for (int u = 0; u < 8; ++u)
            s += (float)qv[u] * (float)kv[u];
    }
    const long e = e0 + g;
    if (e < M) {
        float ev = expf(s * 0.0625f);   // 1/sqrt(256) = 1/16
        out[((size_t)b * M + e) * NHEAD + h] = ev;   // 256B contiguous per wave
        atomicAdd(seg + ((size_t)b * N + src) * NHEAD + h, ev);
    }
}

// ---------------- Normalize: out = e / (seg[src] + 1e-16) -----------------
__global__ __launch_bounds__(256) void norm_kernel(
    const int* __restrict__ mask, const float* __restrict__ seg,
    float* __restrict__ out, int M, int N, int BM)
{
    int idx = blockIdx.x * 256 + threadIdx.x;   // idx = b*M + e
    if (idx >= BM) return;
    int b = idx / M;
    int e = idx - b * M;
    int src = mask[e];
    const float4* s4 = (const float4*)(seg + ((size_t)b * N + src) * NHEAD);
    float4 s0 = s4[0], s1 = s4[1];
    float4* o4 = (float4*)(out + (size_t)idx * NHEAD);
    float4 o0 = o4[0], o1 = o4[1];
    o0.x /= (s0.x + 1e-16f); o0.y /= (s0.y + 1e-16f);
    o0.z /= (s0.z + 1e-16f); o0.w /= (s0.w + 1e-16f);
    o1.x /= (s1.x + 1e-16f); o1.y /= (s1.y + 1e-16f);
    o1.z /= (s1.z + 1e-16f); o1.w /= (s1.w + 1e-16f);
    o4[0] = o0; o4[1] = o1;
}

extern "C" void kernel_launch(void* const* d_in, const int* in_sizes, int n_in,
                              void* d_out, int out_size, void* d_ws, size_t ws_size,
                              hipStream_t stream) {
    const float* x_q  = (const float*)d_in[0];
    const float* x_k  = (const float*)d_in[1];
    const int*   mask = (const int*)d_in[2];
    const float* w_q  = (const float*)d_in[3];
    const float* w_k  = (const float*)d_in[4];
    float* out = (float*)d_out;

    const int M = in_sizes[2] / 2;                 // 320000
    const int N = in_sizes[0] / (BATCH * DHID);    // 10000
    const int Mrows = BATCH * N;                   // 20000

    _Float16* Qh  = (_Float16*)d_ws;
    _Float16* Kh  = Qh  + (size_t)Mrows * DHID;
    _Float16* Wtq = Kh  + (size_t)Mrows * DHID;
    _Float16* Wtk = Wtq + (size_t)DHID * DHID;
    float*    seg = (float*)(Wtk + (size_t)DHID * DHID);

    hipMemsetAsync(seg, 0, (size_t)BATCH * N * NHEAD * sizeof(float), stream);

    dim3 tgrid(DHID / 32, DHID / 32, 2);
    transpose_w<<<tgrid, dim3(32, 8), 0, stream>>>(w_q, w_k, Wtq, Wtk);

    dim3 ggrid((Mrows + 63) / 64, 1, 2);
    gemm_mfma<<<ggrid, 256, 0, stream>>>(x_q, x_k, Wtq, Wtk, Qh, Kh, Mrows);

    // 8 edges per wave, 4 waves per block
    int waves = (M + 7) / 8;
    dim3 egrid((waves + 3) / 4, BATCH);
    edge_kernel<<<egrid, 256, 0, stream>>>(Qh, Kh, mask, out, seg, M, N);

    const int BM = BATCH * M;
    norm_kernel<<<(BM + 255) / 256, 256, 0, stream>>>(mask, seg, out, M, N, BM);
}